// Round 11
// baseline (240.771 us; speedup 1.0000x reference)
//
#include <hip/hip_runtime.h>
#include <hip/hip_bf16.h>

#define S_STEPS 64

typedef __bf16 bf16x8 __attribute__((ext_vector_type(8)));
typedef float  f32x4  __attribute__((ext_vector_type(4)));
typedef int    i32x4  __attribute__((ext_vector_type(4)));

// ---- async 16B global->LDS (wave-uniform base + lane*16 contiguous dest) ----
__device__ __forceinline__ void async16(const void* g, void* l) {
    __builtin_amdgcn_global_load_lds((const __attribute__((address_space(1))) void*)g,
                                     (__attribute__((address_space(3))) void*)l,
                                     16, 0, 0);
}

// =============== merged prep: encoder + W0 bf16x3 split + W1/W2 i8 quant ===============
__global__ void snn_prep(const float4* __restrict__ xv, ushort4* __restrict__ r,
                         const float4* __restrict__ W0, ushort4* __restrict__ w0out,
                         const float4* __restrict__ W1, const float4* __restrict__ W2,
                         char4* __restrict__ w1out, char4* __restrict__ w2out) {
    constexpr int T = 128, F4 = 128;
    constexpr int NB_ENC = 512;
    constexpr int N0_4 = 1024 * 512 / 4;
    constexpr int NB_W0 = N0_4 / 256;
    constexpr int N1_4 = 1024 * 1024 / 4;
    constexpr int N2_4 = 512 * 1024 / 4;
    __shared__ int4 red[4][64];

    const int bid = blockIdx.x;
    if (bid < NB_ENC) {
        const int f4i = threadIdx.x & 63;
        const int tc  = threadIdx.x >> 6;
        const int b   = bid >> 1;
        const int f4  = (bid & 1) * 64 + f4i;
        int c0 = 0, c1 = 0, c2 = 0, c3 = 0;
        if (b > 0) {
            const float4* xb = xv + ((size_t)b * T + tc * 32) * F4 + f4;
            const float4* xp = xb - (size_t)T * F4;
            for (int t = 0; t < 32; ++t) {
                float4 a = xb[(size_t)t * F4];
                float4 p = xp[(size_t)t * F4];
                c0 += (__fsub_rn(a.x, p.x) >= 0.2f) ? 1 : 0;
                c1 += (__fsub_rn(a.y, p.y) >= 0.2f) ? 1 : 0;
                c2 += (__fsub_rn(a.z, p.z) >= 0.2f) ? 1 : 0;
                c3 += (__fsub_rn(a.w, p.w) >= 0.2f) ? 1 : 0;
            }
        }
        red[tc][f4i] = int4{c0, c1, c2, c3};
        __syncthreads();
        if (tc == 0) {
            int4 a = red[0][f4i], bb = red[1][f4i], cc = red[2][f4i], dd = red[3][f4i];
            int s0 = a.x + bb.x + cc.x + dd.x;
            int s1 = a.y + bb.y + cc.y + dd.y;
            int s2 = a.z + bb.z + cc.z + dd.z;
            int s3 = a.w + bb.w + cc.w + dd.w;
            ushort4 o;
            o.x = __hip_bfloat16_raw(__float2bfloat16((float)s0 * (1.0f / 128.0f))).x;
            o.y = __hip_bfloat16_raw(__float2bfloat16((float)s1 * (1.0f / 128.0f))).x;
            o.z = __hip_bfloat16_raw(__float2bfloat16((float)s2 * (1.0f / 128.0f))).x;
            o.w = __hip_bfloat16_raw(__float2bfloat16((float)s3 * (1.0f / 128.0f))).x;
            r[(size_t)b * F4 + f4] = o;
        }
    } else if (bid < NB_ENC + NB_W0) {
        int j = (bid - NB_ENC) * 256 + threadIdx.x;
        float4 w = W0[j];
        float wv[4] = {w.x, w.y, w.z, w.w};
        unsigned short hv[4], mv[4], lv[4];
        #pragma unroll
        for (int q = 0; q < 4; ++q) {
            __hip_bfloat16 hh = __float2bfloat16(wv[q]);
            float r1 = __fsub_rn(wv[q], __bfloat162float(hh));
            __hip_bfloat16 mm = __float2bfloat16(r1);
            float r2 = __fsub_rn(r1, __bfloat162float(mm));
            hv[q] = __hip_bfloat16_raw(hh).x;
            mv[q] = __hip_bfloat16_raw(mm).x;
            lv[q] = __hip_bfloat16_raw(__float2bfloat16(r2)).x;
        }
        w0out[j]             = ushort4{hv[0], hv[1], hv[2], hv[3]};
        w0out[j + N0_4]      = ushort4{mv[0], mv[1], mv[2], mv[3]};
        w0out[j + 2 * N0_4]  = ushort4{lv[0], lv[1], lv[2], lv[3]};
    } else {
        int i = (bid - NB_ENC - NB_W0) * 256 + threadIdx.x;
        const float4* W; char4* out; int n4; int j = i;
        if (j < N1_4) { W = W1; out = w1out; n4 = N1_4; }
        else { j -= N1_4; W = W2; out = w2out; n4 = N2_4; }
        float4 w = W[j];
        float wv[4] = {w.x, w.y, w.z, w.w};
        signed char d2v[4], d1v[4], d0v[4];
        #pragma unroll
        for (int q = 0; q < 4; ++q) {
            int e  = __float2int_rn(wv[q] * 134217728.0f);       // w * 2^27
            int d0 = (int)(signed char)(e & 0xff);
            int e1 = (e - d0) >> 8;
            int d1 = (int)(signed char)(e1 & 0xff);
            int d2 = (e1 - d1) >> 8;
            d0v[q] = (signed char)d0;
            d1v[q] = (signed char)d1;
            d2v[q] = (signed char)d2;
        }
        out[j]          = make_char4(d2v[0], d2v[1], d2v[2], d2v[3]);
        out[j + n4]     = make_char4(d1v[0], d1v[1], d1v[2], d1v[3]);
        out[j + 2 * n4] = make_char4(d0v[0], d0v[1], d0v[2], d0v[3]);
    }
}

// Swizzled staging map (16-row x 64B group = 64 slots x 16B):
//   slot s holds (row = s>>2, chunk16B = ((s&3)+(s>>2)+(s>>4)) & 3)
//   frag read slot(rho,kap) = 4*rho + ((kap - rho - (rho>>2)) & 3)
// B-MAJOR M-LAYOUT: row = b*64 + s; LIF scan fused in epilogues.

// ========== GEMM1 i8, 8-phase 256x256 template (T3+T4+T5) + fused LIF ==========
// M=16384, N=1024, K=1024, 3 parts (Horner).  512 thr = 8 waves (2m x 4n),
// per-wave 128x64.  BK=128 i8.  LDS: 2 buf x 4 quarters {Akh0,Bkh0,Akh1,Bkh1}
// x 16KB = 128KB.  Per K-tile: 4 phases x 16 MFMA; counted vmcnt(4) at end of
// phases 1,3 (quarter q lands one phase-barrier before its reader; never drains).
__global__ __launch_bounds__(512, 2)
void snn_gemm_i8_8ph(const signed char* __restrict__ A,
                     const signed char* __restrict__ Wq,
                     const float* __restrict__ bias,
                     signed char* __restrict__ Sout,
                     int M, int N, int K) {
    __shared__ __align__(16) char Lds[131072];
    const int t    = threadIdx.x;
    const int wave = t >> 6;       // 0..7
    const int lane = t & 63;
    const int wr   = wave >> 2;    // 0..1
    const int wc   = wave & 3;     // 0..3

    int m_idx, n_idx;
    {
        int gx = gridDim.x, gy = gridDim.y;
        int flat = blockIdx.y * gx + blockIdx.x;
        if ((gy & 7) == 0) {
            int x = flat & 7, local = flat >> 3, h = gy >> 3;
            m_idx = x * h + (local % h);
            n_idx = local / h;
        } else { m_idx = blockIdx.y; n_idx = blockIdx.x; }
    }
    const int m0 = m_idx * 256;
    const int n0 = n_idx * 256;

    const int srow = lane >> 2;
    const int schk = ((lane & 3) + (lane >> 2) + (lane >> 4)) & 3;
    const int rho  = lane & 15;
    const int kap  = lane >> 4;
    const int foff = ((rho << 2) + ((kap - rho - (rho >> 2)) & 3)) * 16;   // bytes

    const int KT = K >> 7;              // 8
    const int NT = 3 * KT;              // 24
    const size_t PK = (size_t)N * K;

    // staging bases: wave stages groups 2w, 2w+1 of each quarter (slot = lane)
    const size_t aB0 = (size_t)(m0 + (wave * 2) * 16 + srow) * K;
    const size_t aB1 = aB0 + (size_t)16 * K;
    const size_t bB0 = (size_t)(n0 + (wave * 2) * 16 + srow) * K;
    const size_t bB1 = bB0 + (size_t)16 * K;
    const int sOff = schk * 16;

    i32x4 acc[8][4] = {};
    i32x4 af[4], bf[4];

    auto stageQ = [&](int p, int kt, int q, int bsel) {
        const size_t ko = (size_t)(kt << 7) + ((q >> 1) << 6) + sOff;
        char* d = Lds + (((bsel << 2) + q) << 14) + (wave << 11) + lane * 16;
        if (!(q & 1)) {
            async16(A + aB0 + ko, d);
            async16(A + aB1 + ko, d + 1024);
        } else {
            const signed char* Bw = Wq + (size_t)p * PK;
            async16(Bw + bB0 + ko, d);
            async16(Bw + bB1 + ko, d + 1024);
        }
    };
    auto ldA = [&](int mh, int kh, int b) {
        const char* base = Lds + (((b << 2) + (kh << 1)) << 14) + foff;
        #pragma unroll
        for (int q = 0; q < 4; ++q)
            af[q] = *(const i32x4*)(base + (wr * 8 + mh * 4 + q) * 1024);
    };
    auto ldB = [&](int kh, int b) {
        const char* base = Lds + (((b << 2) + (kh << 1) + 1) << 14) + foff;
        #pragma unroll
        for (int q = 0; q < 4; ++q)
            bf[q] = *(const i32x4*)(base + (wc * 4 + q) * 1024);
    };
    auto mmac = [&](int mh) {
        #pragma unroll
        for (int q = 0; q < 4; ++q)
            #pragma unroll
            for (int j = 0; j < 4; ++j)
                acc[mh * 4 + q][j] = __builtin_amdgcn_mfma_i32_16x16x64_i8(af[q], bf[j], acc[mh * 4 + q][j], 0, 0, 0);
    };

    // prologue: stage all 4 quarters of tile 0 into buf 0
    stageQ(0, 0, 0, 0); stageQ(0, 0, 1, 0); stageQ(0, 0, 2, 0); stageQ(0, 0, 3, 0);
    int sp = 0, skt = 1;                 // next tile to stage = tile 1
    asm volatile("s_waitcnt vmcnt(4)" ::: "memory");   // q0,q1 of tile 0 landed
    __builtin_amdgcn_s_barrier();

    for (int i = 0; i < NT; ++i) {
        const int b = i & 1;
        const bool st = (i + 1 < NT);
        // ---- phase 0: (mh0, kh0) ----
        if (st) stageQ(sp, skt, 0, b ^ 1);
        ldA(0, 0, b); ldB(0, b);
        __builtin_amdgcn_s_barrier();
        asm volatile("s_waitcnt lgkmcnt(0)" ::: "memory");
        __builtin_amdgcn_sched_barrier(0);
        if (i == KT || i == 2 * KT) {                 // Horner fold at part edges
            #pragma unroll
            for (int q = 0; q < 8; ++q)
                #pragma unroll
                for (int j = 0; j < 4; ++j)
                    acc[q][j] = acc[q][j] * 256;
        }
        __builtin_amdgcn_s_setprio(1); mmac(0); __builtin_amdgcn_s_setprio(0);
        __builtin_amdgcn_s_barrier();
        // ---- phase 1: (mh1, kh0) ----
        if (st) stageQ(sp, skt, 1, b ^ 1);
        ldA(1, 0, b);
        __builtin_amdgcn_s_barrier();
        asm volatile("s_waitcnt lgkmcnt(0)" ::: "memory");
        __builtin_amdgcn_sched_barrier(0);
        __builtin_amdgcn_s_setprio(1); mmac(1); __builtin_amdgcn_s_setprio(0);
        if (st) asm volatile("s_waitcnt vmcnt(4)" ::: "memory");   // this tile's q2,q3 landed
        else    asm volatile("s_waitcnt vmcnt(0)" ::: "memory");
        __builtin_amdgcn_s_barrier();
        // ---- phase 2: (mh0, kh1) ----
        if (st) stageQ(sp, skt, 2, b ^ 1);
        ldA(0, 1, b); ldB(1, b);
        __builtin_amdgcn_s_barrier();
        asm volatile("s_waitcnt lgkmcnt(0)" ::: "memory");
        __builtin_amdgcn_sched_barrier(0);
        __builtin_amdgcn_s_setprio(1); mmac(0); __builtin_amdgcn_s_setprio(0);
        __builtin_amdgcn_s_barrier();
        // ---- phase 3: (mh1, kh1) ----
        if (st) stageQ(sp, skt, 3, b ^ 1);
        ldA(1, 1, b);
        __builtin_amdgcn_s_barrier();
        asm volatile("s_waitcnt lgkmcnt(0)" ::: "memory");
        __builtin_amdgcn_sched_barrier(0);
        __builtin_amdgcn_s_setprio(1); mmac(1); __builtin_amdgcn_s_setprio(0);
        if (st) asm volatile("s_waitcnt vmcnt(4)" ::: "memory");   // next tile's q0,q1 landed
        __builtin_amdgcn_s_barrier();
        if (st) { if (++skt == KT) { skt = 0; ++sp; } }
    }

    // ---------- fused LIF epilogue (2 batch-blocks per wave) ----------
    const float SCALE = 7.450580596923828e-9f;   // 2^-27
    float bb[4];
    #pragma unroll
    for (int j = 0; j < 4; ++j)
        bb[j] = bias[n0 + wc * 64 + j * 16 + rho];
    #pragma unroll
    for (int q = 0; q < 8; ++q)
        #pragma unroll
        for (int j = 0; j < 4; ++j) {
            i32x4 v = acc[q][j];
            f32x4 c;
            #pragma unroll
            for (int r = 0; r < 4; ++r)
                c[r] = (float)v[r] * SCALE + bb[j];
            acc[q][j] = __builtin_bit_cast(i32x4, c);
        }
    #pragma unroll
    for (int bi = 0; bi < 2; ++bi) {
        float mj[4] = {0.f, 0.f, 0.f, 0.f};
        signed char* So = Sout + (size_t)(m0 + wr * 128 + bi * 64) * N;
        #pragma unroll
        for (int seg = 0; seg < 16; ++seg) {
            const int si = seg >> 2, sk = seg & 3;
            const int src = rho | (((sk + 3) & 3) << 4);
            #pragma unroll
            for (int j = 0; j < 4; ++j) {
                float tin = __shfl(mj[j], src);
                if (seg > 0 && kap == sk) mj[j] = tin;
            }
            if (kap == sk) {
                #pragma unroll
                for (int j = 0; j < 4; ++j) {
                    f32x4 c = __builtin_bit_cast(f32x4, acc[bi * 4 + si][j]);
                    const int ng = n0 + wc * 64 + j * 16 + rho;
                    #pragma unroll
                    for (int r = 0; r < 4; ++r) {
                        float rst = (mj[j] > 1.0f) ? 1.0f : 0.0f;
                        mj[j] = __fsub_rn(__fadd_rn(__fmul_rn(0.9f, mj[j]), c[r]), rst);
                        So[(size_t)(seg * 4 + r) * N + ng] = (mj[j] > 1.0f) ? (signed char)1 : (signed char)0;
                    }
                }
            }
        }
    }
}

// ============ GEMM2 i8 + fused LIF -> f32 (R7-verified structure) ============
__global__ __launch_bounds__(256, 2)
void snn_gemm_i8_n_lif(const signed char* __restrict__ A,
                       const signed char* __restrict__ Wq,
                       const float* __restrict__ bias,
                       float* __restrict__ Dout,        // [S, Bsz, N] f32 spikes
                       int M, int N, int K, int Bsz) {
    __shared__ __align__(16) char As[3 * 8192];
    __shared__ __align__(16) char Bs[3 * 8192];
    const int t    = threadIdx.x;
    const int wave = t >> 6;
    const int lane = t & 63;

    int m_idx, n_idx;
    {
        int gx = gridDim.x, gy = gridDim.y;
        int flat = blockIdx.y * gx + blockIdx.x;
        if ((gy & 7) == 0) {
            int x = flat & 7, local = flat >> 3, h = gy >> 3;
            m_idx = x * h + (local % h);
            n_idx = local / h;
        } else { m_idx = blockIdx.y; n_idx = blockIdx.x; }
    }
    const int m0 = m_idx * 128;
    const int n0 = n_idx * 128;
    const int wm = (wave & 1) * 64;
    const int wn = (wave >> 1) * 64;

    const int srow = lane >> 2;
    const int schk = ((lane & 3) + (lane >> 2) + (lane >> 4)) & 3;
    const int rho  = lane & 15;
    const int kap  = lane >> 4;
    const int foff = ((rho << 2) + ((kap - rho - (rho >> 2)) & 3)) * 16;   // bytes

    const int KT = K >> 6;
    const int NT = 3 * KT;
    const size_t PK = (size_t)N * K;

    size_t aOff[2], bOff[2];
    #pragma unroll
    for (int q = 0; q < 2; ++q) {
        aOff[q] = (size_t)(m0 + (wave * 2 + q) * 16 + srow) * K + schk * 16;
        bOff[q] = (size_t)(n0 + (wave * 2 + q) * 16 + srow) * K + schk * 16;
    }

    i32x4 acc[4][4] = {};
    i32x4 afA[4], afB[4], bLo[2], bHi[2];

    auto stageT = [&](int p, int kt, int bsel) {
        const int kk = kt << 6;
        char* as = As + bsel * 8192;
        char* bs = Bs + bsel * 8192;
        const signed char* Bw = Wq + (size_t)p * PK;
        #pragma unroll
        for (int q = 0; q < 2; ++q) {
            async16(A  + aOff[q] + kk, as + (wave * 2 + q) * 1024 + lane * 16);
            async16(Bw + bOff[q] + kk, bs + (wave * 2 + q) * 1024 + lane * 16);
        }
    };

    int sp = 0, skt = 2;
    int sbuf = 2, rbuf = 1;

    auto body = [&](int i, i32x4* afc, i32x4* afn) {
        if (i + 2 < NT) {
            stageT(sp, skt, sbuf);
            if (++skt == KT) { skt = 0; ++sp; }
            asm volatile("s_waitcnt vmcnt(4)" ::: "memory");
        } else {
            asm volatile("s_waitcnt vmcnt(0)" ::: "memory");
        }
        __builtin_amdgcn_s_barrier();
        const char* as = As + rbuf * 8192;
        const char* bs = Bs + rbuf * 8192;
        #pragma unroll
        for (int q = 0; q < 4; ++q)
            afn[q] = *(const i32x4*)&as[((wm >> 4) + q) * 1024 + foff];
        #pragma unroll
        for (int q = 0; q < 2; ++q)
            bLo[q] = *(const i32x4*)&bs[((wn >> 4) + q) * 1024 + foff];
        __builtin_amdgcn_sched_barrier(0);
        #pragma unroll
        for (int q = 0; q < 4; ++q)
            #pragma unroll
            for (int j = 0; j < 2; ++j)
                acc[q][2 + j] = __builtin_amdgcn_mfma_i32_16x16x64_i8(afc[q], bHi[j], acc[q][2 + j], 0, 0, 0);
        #pragma unroll
        for (int q = 0; q < 2; ++q)
            bHi[q] = *(const i32x4*)&bs[((wn >> 4) + 2 + q) * 1024 + foff];
        asm volatile("s_waitcnt lgkmcnt(0)" ::: "memory");
        __builtin_amdgcn_sched_barrier(0);
        if (((i + 1) & (KT - 1)) == 0) {
            #pragma unroll
            for (int q = 0; q < 4; ++q)
                #pragma unroll
                for (int j = 0; j < 4; ++j)
                    acc[q][j] = acc[q][j] * 256;
        }
        #pragma unroll
        for (int q = 0; q < 4; ++q)
            #pragma unroll
            for (int j = 0; j < 2; ++j)
                acc[q][j] = __builtin_amdgcn_mfma_i32_16x16x64_i8(afn[q], bLo[j], acc[q][j], 0, 0, 0);
        sbuf = (sbuf == 2) ? 0 : sbuf + 1;
        rbuf = (rbuf == 2) ? 0 : rbuf + 1;
    };

    stageT(0, 0, 0);
    stageT(0, 1, 1);
    asm volatile("s_waitcnt vmcnt(4)" ::: "memory");
    __builtin_amdgcn_s_barrier();
    {
        const char* as = As;
        const char* bs = Bs;
        #pragma unroll
        for (int q = 0; q < 4; ++q)
            afA[q] = *(const i32x4*)&as[((wm >> 4) + q) * 1024 + foff];
        #pragma unroll
        for (int q = 0; q < 2; ++q) {
            bLo[q] = *(const i32x4*)&bs[((wn >> 4) + q) * 1024 + foff];
            bHi[q] = *(const i32x4*)&bs[((wn >> 4) + 2 + q) * 1024 + foff];
        }
    }
    asm volatile("s_waitcnt lgkmcnt(0)" ::: "memory");
    __builtin_amdgcn_sched_barrier(0);
    #pragma unroll
    for (int q = 0; q < 4; ++q)
        #pragma unroll
        for (int j = 0; j < 2; ++j)
            acc[q][j] = __builtin_amdgcn_mfma_i32_16x16x64_i8(afA[q], bLo[j], acc[q][j], 0, 0, 0);

    for (int i = 0; i < NT - 2; i += 2) {
        body(i, afA, afB);
        body(i + 1, afB, afA);
    }
    body(NT - 2, afA, afB);
    #pragma unroll
    for (int q = 0; q < 4; ++q)
        #pragma unroll
        for (int j = 0; j < 2; ++j)
            acc[q][2 + j] = __builtin_amdgcn_mfma_i32_16x16x64_i8(afB[q], bHi[j], acc[q][2 + j], 0, 0, 0);

    const float SCALE = 7.450580596923828e-9f;   // 2^-27
    float bb[4];
    #pragma unroll
    for (int j = 0; j < 4; ++j)
        bb[j] = bias[n0 + wn + j * 16 + (lane & 15)];
    #pragma unroll
    for (int i = 0; i < 4; ++i)
        #pragma unroll
        for (int j = 0; j < 4; ++j) {
            i32x4 v = acc[i][j];
            f32x4 c;
            #pragma unroll
            for (int r = 0; r < 4; ++r)
                c[r] = (float)v[r] * SCALE + bb[j];
            acc[i][j] = __builtin_bit_cast(i32x4, c);
        }
    float mj[4] = {0.f, 0.f, 0.f, 0.f};
    const int b_idx = (m0 + wm) >> 6;
    #pragma unroll
    for (int seg = 0; seg < 16; ++seg) {
        const int si = seg >> 2, sk = seg & 3;
        const int src = (lane & 15) | (((sk + 3) & 3) << 4);
        #pragma unroll
        for (int j = 0; j < 4; ++j) {
            float tin = __shfl(mj[j], src);
            if (seg > 0 && kap == sk) mj[j] = tin;
        }
        if (kap == sk) {
            #pragma unroll
            for (int j = 0; j < 4; ++j) {
                f32x4 c = __builtin_bit_cast(f32x4, acc[si][j]);
                const int ng = n0 + wn + j * 16 + (lane & 15);
                #pragma unroll
                for (int r = 0; r < 4; ++r) {
                    float rst = (mj[j] > 1.0f) ? 1.0f : 0.0f;
                    mj[j] = __fsub_rn(__fadd_rn(__fmul_rn(0.9f, mj[j]), c[r]), rst);
                    Dout[((size_t)(seg * 4 + r) * Bsz + b_idx) * N + ng] = (mj[j] > 1.0f) ? 1.0f : 0.0f;
                }
            }
        }
    }
}

// ========== GEMM0 bf16, per-part blocks, pipelined (R10-verified) ==========
__global__ __launch_bounds__(256, 2)
void snn_gemm0_bf16p(const __hip_bfloat16* __restrict__ A,
                     const __hip_bfloat16* __restrict__ Wp,
                     float* __restrict__ Cpart) {
    constexpr int M = 256, N = 1024, K = 512;
    constexpr int KT = K / 32;
    __shared__ __align__(16) char As[3 * 8192];
    __shared__ __align__(16) char Bs[3 * 8192];
    const int t    = threadIdx.x;
    const int wave = t >> 6;
    const int lane = t & 63;

    const int part = blockIdx.z;
    const __hip_bfloat16* Bw = Wp + (size_t)part * N * K;
    float* C = Cpart + (size_t)part * M * N;
    const int m0 = blockIdx.y * 128;
    const int n0 = blockIdx.x * 128;
    const int wm = (wave & 1) * 64;
    const int wn = (wave >> 1) * 64;

    const int srow = lane >> 2;
    const int schk = ((lane & 3) + (lane >> 2) + (lane >> 4)) & 3;
    const int rho  = lane & 15;
    const int kap  = lane >> 4;
    const int foff = ((rho << 2) + ((kap - rho - (rho >> 2)) & 3)) * 16;   // bytes

    size_t aOff[2], bOff[2];
    #pragma unroll
    for (int q = 0; q < 2; ++q) {
        aOff[q] = (size_t)(m0 + (wave * 2 + q) * 16 + srow) * K + schk * 8;
        bOff[q] = (size_t)(n0 + (wave * 2 + q) * 16 + srow) * K + schk * 8;
    }

    f32x4 acc[4][4] = {};
    bf16x8 afA[4], afB[4], bLo[2], bHi[2];

    auto stageT = [&](int kt, int bsel) {
        const int kk = kt << 5;
        char* as = As + bsel * 8192;
        char* bs = Bs + bsel * 8192;
        #pragma unroll
        for (int q = 0; q < 2; ++q) {
            async16(A  + aOff[q] + kk, as + (wave * 2 + q) * 1024 + lane * 16);
            async16(Bw + bOff[q] + kk, bs + (wave * 2 + q) * 1024 + lane * 16);
        }
    };

    int skt = 2;
    int sbuf = 2, rbuf = 1;

    auto body = [&](int i, bf16x8* afc, bf16x8* afn) {
        if (i + 2 < KT) {
            stageT(skt, sbuf);
            ++skt;
            asm volatile("s_waitcnt vmcnt(4)" ::: "memory");
        } else {
            asm volatile("s_waitcnt vmcnt(0)" ::: "memory");
        }
        __builtin_amdgcn_s_barrier();
        const char* as = As + rbuf * 8192;
        const char* bs = Bs + rbuf * 8192;
        #pragma unroll
        for (int q = 0; q < 4; ++q)
            afn[q] = *(const bf16x8*)&as[((wm >> 4) + q) * 1024 + foff];
        #pragma unroll
        for (int q = 0; q < 2; ++q)
            bLo[q] = *(const bf16x8*)&bs[((wn >> 4) + q) * 1024 + foff];
        __builtin_amdgcn_sched_barrier(0);
        #pragma unroll
        for (int q = 0; q < 4; ++q)
            #pragma unroll
            for (int j = 0; j < 2; ++j)
                acc[q][2 + j] = __builtin_amdgcn_mfma_f32_16x16x32_bf16(afc[q], bHi[j], acc[q][2 + j], 0, 0, 0);
        #pragma unroll
        for (int q = 0; q < 2; ++q)
            bHi[q] = *(const bf16x8*)&bs[((wn >> 4) + 2 + q) * 1024 + foff];
        asm volatile("s_waitcnt lgkmcnt(0)" ::: "memory");
        __builtin_amdgcn_sched_barrier(0);
        #pragma unroll
        for (int q = 0; q < 4; ++q)
            #pragma unroll
            for (int j = 0; j < 2; ++j)
                acc[q][j] = __builtin_amdgcn_mfma_f32_16x16x32_bf16(afn[q], bLo[j], acc[q][j], 0, 0, 0);
        sbuf = (sbuf == 2) ? 0 : sbuf + 1;
        rbuf = (rbuf == 2) ? 0 : rbuf + 1;
    };

    stageT(0, 0);
    stageT(1, 1);
    asm volatile("s_waitcnt vmcnt(4)" ::: "memory");
    __builtin_amdgcn_s_barrier();
    {
        const char* as = As;
        const char* bs = Bs;
        #pragma unroll
        for (int q = 0; q < 4; ++q)
            afA[q] = *(const bf16x8*)&as[((wm >> 4) + q) * 1024 + foff];
        #pragma unroll
        for (int q = 0; q < 2; ++q) {
            bLo[q] = *(const bf16x8*)&bs[((wn >> 4) + q) * 1024 + foff];
            bHi[q] = *(const bf16x8*)&bs[((wn >> 4) + 2 + q) * 1024 + foff];
        }
    }
    asm volatile("s_waitcnt lgkmcnt(0)" ::: "memory");
    __builtin_amdgcn_sched_barrier(0);
    #pragma unroll
    for (int q = 0; q < 4; ++q)
        #pragma unroll
        for (int j = 0; j < 2; ++j)
            acc[q][j] = __builtin_amdgcn_mfma_f32_16x16x32_bf16(afA[q], bLo[j], acc[q][j], 0, 0, 0);

    for (int i = 0; i < KT - 2; i += 2) {
        body(i, afA, afB);
        body(i + 1, afB, afA);
    }
    body(KT - 2, afA, afB);
    #pragma unroll
    for (int q = 0; q < 4; ++q)
        #pragma unroll
        for (int j = 0; j < 2; ++j)
            acc[q][2 + j] = __builtin_amdgcn_mfma_f32_16x16x32_bf16(afB[q], bHi[j], acc[q][2 + j], 0, 0, 0);

    #pragma unroll
    for (int i = 0; i < 4; ++i) {
        int mg = m0 + wm + i * 16 + (lane >> 4) * 4;
        #pragma unroll
        for (int j = 0; j < 4; ++j) {
            int ng = n0 + wn + j * 16 + (lane & 15);
            #pragma unroll
            for (int r = 0; r < 4; ++r)
                C[(size_t)(mg + r) * N + ng] = acc[i][j][r];
        }
    }
}

// -------- LIF layer 0: sum 3 part-slabs + bias, scan, b-major i8 spikes --------
__global__ void snn_lif0_sum3(const float4* __restrict__ p, const float4* __restrict__ b4,
                              uchar4* __restrict__ spk) {
    constexpr int MN4 = 256 * 1024 / 4;
    constexpr int H4  = 256;
    int idx = blockIdx.x * blockDim.x + threadIdx.x;
    if (idx >= MN4) return;
    const int b  = idx >> 8;
    const int h4 = idx & 255;
    float4 h = p[idx], mm = p[idx + MN4], l = p[idx + 2 * MN4], bb = b4[h4];
    float4 c;
    c.x = __fadd_rn(__fadd_rn(__fadd_rn(h.x, mm.x), l.x), bb.x);
    c.y = __fadd_rn(__fadd_rn(__fadd_rn(h.y, mm.y), l.y), bb.y);
    c.z = __fadd_rn(__fadd_rn(__fadd_rn(h.z, mm.z), l.z), bb.z);
    c.w = __fadd_rn(__fadd_rn(__fadd_rn(h.w, mm.w), l.w), bb.w);
    uchar4* out = spk + (size_t)b * S_STEPS * H4 + h4;
    float m0 = 0.0f, m1 = 0.0f, m2 = 0.0f, m3 = 0.0f;
    for (int s = 0; s < S_STEPS; ++s) {
        float r0 = (m0 > 1.0f) ? 1.0f : 0.0f;
        float r1 = (m1 > 1.0f) ? 1.0f : 0.0f;
        float r2 = (m2 > 1.0f) ? 1.0f : 0.0f;
        float r3 = (m3 > 1.0f) ? 1.0f : 0.0f;
        m0 = __fsub_rn(__fadd_rn(__fmul_rn(0.9f, m0), c.x), r0);
        m1 = __fsub_rn(__fadd_rn(__fmul_rn(0.9f, m1), c.y), r1);
        m2 = __fsub_rn(__fadd_rn(__fmul_rn(0.9f, m2), c.z), r2);
        m3 = __fsub_rn(__fadd_rn(__fmul_rn(0.9f, m3), c.w), r3);
        uchar4 o;
        o.x = (m0 > 1.0f) ? 1 : 0;
        o.y = (m1 > 1.0f) ? 1 : 0;
        o.z = (m2 > 1.0f) ? 1 : 0;
        o.w = (m3 > 1.0f) ? 1 : 0;
        out[(size_t)s * H4] = o;
    }
}

extern "C" void kernel_launch(void* const* d_in, const int* in_sizes, int n_in,
                              void* d_out, int out_size, void* d_ws, size_t ws_size,
                              hipStream_t stream) {
    const float* x  = (const float*)d_in[0];
    const float* W0 = (const float*)d_in[1];
    const float* b0 = (const float*)d_in[2];
    const float* W1 = (const float*)d_in[3];
    const float* b1 = (const float*)d_in[4];
    const float* W2 = (const float*)d_in[5];
    const float* b2 = (const float*)d_in[6];

    const int B = 256, T = 128, F = 512, H1 = 1024, H2 = 1024, H3 = 512;
    const int SB = S_STEPS * B;            // 16384

    char* w = (char*)d_ws;
    signed char*    spk0 = (signed char*)w;                 w += (size_t)SB * H1;
    signed char*    spk1 = (signed char*)w;                 w += (size_t)SB * H2;
    __hip_bfloat16* r_bf = (__hip_bfloat16*)w;              w += (size_t)B * F * 2;
    float*          cur0p = (float*)w;                      w += (size_t)3 * B * H1 * 4;
    __hip_bfloat16* W0s  = (__hip_bfloat16*)w;              w += (size_t)3 * H1 * F * 2;
    signed char*    W1q  = (signed char*)w;                 w += (size_t)3 * H2 * H1;
    signed char*    W2q  = (signed char*)w;                 w += (size_t)3 * H3 * H2;

    // 1. merged prep
    snn_prep<<<dim3(2560), dim3(256), 0, stream>>>(
        (const float4*)x, (ushort4*)r_bf,
        (const float4*)W0, (ushort4*)W0s,
        (const float4*)W1, (const float4*)W2,
        (char4*)W1q, (char4*)W2q);

    // 2. GEMM0 per part, pipelined
    snn_gemm0_bf16p<<<dim3(H1 / 128, B / 128, 3), dim3(256), 0, stream>>>(
        r_bf, W0s, cur0p);

    // 3. LIF layer 0: sum parts + bias, scan -> spk0 i8 b-major
    snn_lif0_sum3<<<dim3(B * H1 / 4 / 256), dim3(256), 0, stream>>>(
        (const float4*)cur0p, (const float4*)b0, (uchar4*)spk0);

    // 4+5. GEMM1 8-phase 256x256 + fused LIF -> spk1 i8 b-major
    snn_gemm_i8_8ph<<<dim3(H2 / 256, SB / 256), dim3(512), 0, stream>>>(
        spk0, W1q, b1, spk1, SB, H2, H1);

    // 6+7. GEMM2 + fused LIF -> d_out f32 [S, B, H3]
    snn_gemm_i8_n_lif<<<dim3(H3 / 128, SB / 128), dim3(256), 0, stream>>>(
        spk1, W2q, b2, (float*)d_out, SB, H3, H2, B);
}

// Round 12
// 214.532 us; speedup vs baseline: 1.1223x; 1.1223x over previous
//
#include <hip/hip_runtime.h>
#include <hip/hip_bf16.h>

#define S_STEPS 64

typedef __bf16 bf16x8 __attribute__((ext_vector_type(8)));
typedef float  f32x4  __attribute__((ext_vector_type(4)));
typedef int    i32x4  __attribute__((ext_vector_type(4)));

// ---- async 16B global->LDS (wave-uniform base + lane*16 contiguous dest) ----
__device__ __forceinline__ void async16(const void* g, void* l) {
    __builtin_amdgcn_global_load_lds((const __attribute__((address_space(1))) void*)g,
                                     (__attribute__((address_space(3))) void*)l,
                                     16, 0, 0);
}

// =============== merged prep: encoder + W0 bf16x3 split + W1/W2 i8 quant ===============
__global__ void snn_prep(const float4* __restrict__ xv, ushort4* __restrict__ r,
                         const float4* __restrict__ W0, ushort4* __restrict__ w0out,
                         const float4* __restrict__ W1, const float4* __restrict__ W2,
                         char4* __restrict__ w1out, char4* __restrict__ w2out) {
    constexpr int T = 128, F4 = 128;
    constexpr int NB_ENC = 512;
    constexpr int N0_4 = 1024 * 512 / 4;
    constexpr int NB_W0 = N0_4 / 256;
    constexpr int N1_4 = 1024 * 1024 / 4;
    constexpr int N2_4 = 512 * 1024 / 4;
    __shared__ int4 red[4][64];

    const int bid = blockIdx.x;
    if (bid < NB_ENC) {
        const int f4i = threadIdx.x & 63;
        const int tc  = threadIdx.x >> 6;
        const int b   = bid >> 1;
        const int f4  = (bid & 1) * 64 + f4i;
        int c0 = 0, c1 = 0, c2 = 0, c3 = 0;
        if (b > 0) {
            const float4* xb = xv + ((size_t)b * T + tc * 32) * F4 + f4;
            const float4* xp = xb - (size_t)T * F4;
            for (int t = 0; t < 32; ++t) {
                float4 a = xb[(size_t)t * F4];
                float4 p = xp[(size_t)t * F4];
                c0 += (__fsub_rn(a.x, p.x) >= 0.2f) ? 1 : 0;
                c1 += (__fsub_rn(a.y, p.y) >= 0.2f) ? 1 : 0;
                c2 += (__fsub_rn(a.z, p.z) >= 0.2f) ? 1 : 0;
                c3 += (__fsub_rn(a.w, p.w) >= 0.2f) ? 1 : 0;
            }
        }
        red[tc][f4i] = int4{c0, c1, c2, c3};
        __syncthreads();
        if (tc == 0) {
            int4 a = red[0][f4i], bb = red[1][f4i], cc = red[2][f4i], dd = red[3][f4i];
            int s0 = a.x + bb.x + cc.x + dd.x;
            int s1 = a.y + bb.y + cc.y + dd.y;
            int s2 = a.z + bb.z + cc.z + dd.z;
            int s3 = a.w + bb.w + cc.w + dd.w;
            ushort4 o;
            o.x = __hip_bfloat16_raw(__float2bfloat16((float)s0 * (1.0f / 128.0f))).x;
            o.y = __hip_bfloat16_raw(__float2bfloat16((float)s1 * (1.0f / 128.0f))).x;
            o.z = __hip_bfloat16_raw(__float2bfloat16((float)s2 * (1.0f / 128.0f))).x;
            o.w = __hip_bfloat16_raw(__float2bfloat16((float)s3 * (1.0f / 128.0f))).x;
            r[(size_t)b * F4 + f4] = o;
        }
    } else if (bid < NB_ENC + NB_W0) {
        int j = (bid - NB_ENC) * 256 + threadIdx.x;
        float4 w = W0[j];
        float wv[4] = {w.x, w.y, w.z, w.w};
        unsigned short hv[4], mv[4], lv[4];
        #pragma unroll
        for (int q = 0; q < 4; ++q) {
            __hip_bfloat16 hh = __float2bfloat16(wv[q]);
            float r1 = __fsub_rn(wv[q], __bfloat162float(hh));
            __hip_bfloat16 mm = __float2bfloat16(r1);
            float r2 = __fsub_rn(r1, __bfloat162float(mm));
            hv[q] = __hip_bfloat16_raw(hh).x;
            mv[q] = __hip_bfloat16_raw(mm).x;
            lv[q] = __hip_bfloat16_raw(__float2bfloat16(r2)).x;
        }
        w0out[j]             = ushort4{hv[0], hv[1], hv[2], hv[3]};
        w0out[j + N0_4]      = ushort4{mv[0], mv[1], mv[2], mv[3]};
        w0out[j + 2 * N0_4]  = ushort4{lv[0], lv[1], lv[2], lv[3]};
    } else {
        int i = (bid - NB_ENC - NB_W0) * 256 + threadIdx.x;
        const float4* W; char4* out; int n4; int j = i;
        if (j < N1_4) { W = W1; out = w1out; n4 = N1_4; }
        else { j -= N1_4; W = W2; out = w2out; n4 = N2_4; }
        float4 w = W[j];
        float wv[4] = {w.x, w.y, w.z, w.w};
        signed char d2v[4], d1v[4], d0v[4];
        #pragma unroll
        for (int q = 0; q < 4; ++q) {
            int e  = __float2int_rn(wv[q] * 134217728.0f);       // w * 2^27
            int d0 = (int)(signed char)(e & 0xff);
            int e1 = (e - d0) >> 8;
            int d1 = (int)(signed char)(e1 & 0xff);
            int d2 = (e1 - d1) >> 8;
            d0v[q] = (signed char)d0;
            d1v[q] = (signed char)d1;
            d2v[q] = (signed char)d2;
        }
        out[j]          = make_char4(d2v[0], d2v[1], d2v[2], d2v[3]);
        out[j + n4]     = make_char4(d1v[0], d1v[1], d1v[2], d1v[3]);
        out[j + 2 * n4] = make_char4(d0v[0], d0v[1], d0v[2], d0v[3]);
    }
}

// Swizzled staging map (16-row x 64B group = 64 slots x 16B):
//   slot s holds (row = s>>2, chunk16B = ((s&3)+(s>>2)+(s>>4)) & 3)
//   frag read slot(rho,kap) = 4*rho + ((kap - rho - (rho>>2)) & 3)
// B-MAJOR M-LAYOUT: row = b*64 + s; LIF scan fused in epilogues.
//
// LIF EPILOGUE (LDS-transpose): dump cur to per-wave LDS region [col][s] f32
// (chunk k = s>>2, XOR-swizzled: off = col*256 + (k^(col&7))*16), then each lane
// scans its own column fully in registers (no shfl), stores wave-coalesced.
//
// TRIPLE-BUFFERED, ONE BARRIER PER TILE (R7/R10-verified); M,N,K runtime so the
// tile loop cannot fully unroll (R8: full unroll -> VGPR spill).

// ================= i8 GEMM A + fused LIF: block 128x256, wave 64x128 =================
__global__ __launch_bounds__(256, 2)
void snn_gemm_i8_w_lif(const signed char* __restrict__ A,
                       const signed char* __restrict__ Wq,
                       const float* __restrict__ bias,
                       signed char* __restrict__ Sout,   // spikes i8, rows b*64+s
                       int M, int N, int K) {
    __shared__ __align__(16) char Smem[73728];     // main: As 24KB + Bs 48KB; epi: 4x16KB
    char* As = Smem;
    char* Bs = Smem + 24576;
    const int t    = threadIdx.x;
    const int wave = t >> 6;
    const int lane = t & 63;

    int m_idx, n_idx;
    {
        int gx = gridDim.x, gy = gridDim.y;
        int flat = blockIdx.y * gx + blockIdx.x;
        if ((gy & 7) == 0) {
            int x = flat & 7, local = flat >> 3, h = gy >> 3;
            m_idx = x * h + (local % h);
            n_idx = local / h;
        } else { m_idx = blockIdx.y; n_idx = blockIdx.x; }
    }
    const int m0 = m_idx * 128;
    const int n0 = n_idx * 256;
    const int wm = (wave >> 1) * 64;
    const int wn = (wave & 1) * 128;

    const int srow = lane >> 2;
    const int schk = ((lane & 3) + (lane >> 2) + (lane >> 4)) & 3;
    const int rho  = lane & 15;
    const int kap  = lane >> 4;
    const int foff = ((rho << 2) + ((kap - rho - (rho >> 2)) & 3)) * 16;   // bytes

    const int KT = K >> 6;
    const int NT = 3 * KT;
    const size_t PK = (size_t)N * K;

    size_t aOff[2], bOff[4];
    #pragma unroll
    for (int q = 0; q < 2; ++q)
        aOff[q] = (size_t)(m0 + (wave * 2 + q) * 16 + srow) * K + schk * 16;
    #pragma unroll
    for (int q = 0; q < 4; ++q)
        bOff[q] = (size_t)(n0 + (wave * 4 + q) * 16 + srow) * K + schk * 16;

    i32x4 acc[4][8] = {};
    i32x4 afA[4], afB[4], bLo[4], bHi[4];

    auto stageT = [&](int p, int kt, int bsel) {
        const int kk = kt << 6;
        char* as = As + bsel * 8192;
        char* bs = Bs + bsel * 16384;
        #pragma unroll
        for (int q = 0; q < 2; ++q)
            async16(A + aOff[q] + kk, as + (wave * 2 + q) * 1024 + lane * 16);
        const signed char* Bw = Wq + (size_t)p * PK;
        #pragma unroll
        for (int q = 0; q < 4; ++q)
            async16(Bw + bOff[q] + kk, bs + (wave * 4 + q) * 1024 + lane * 16);
    };

    int sp = 0, skt = 2;          // next tile to stage
    int sbuf = 2, rbuf = 1;       // stage buffer (i+2)%3, read buffer (i+1)%3

    auto body = [&](int i, i32x4* afc, i32x4* afn) {
        if (i + 2 < NT) {
            stageT(sp, skt, sbuf);
            if (++skt == KT) { skt = 0; ++sp; }
            asm volatile("s_waitcnt vmcnt(6)" ::: "memory");   // tile i+1 landed
        } else {
            asm volatile("s_waitcnt vmcnt(0)" ::: "memory");
        }
        __builtin_amdgcn_s_barrier();                          // tile i+1 visible
        const char* as = As + rbuf * 8192;
        const char* bs = Bs + rbuf * 16384;
        #pragma unroll
        for (int q = 0; q < 4; ++q)
            afn[q] = *(const i32x4*)&as[((wm >> 4) + q) * 1024 + foff];
        #pragma unroll
        for (int q = 0; q < 4; ++q)
            bLo[q] = *(const i32x4*)&bs[((wn >> 4) + q) * 1024 + foff];
        __builtin_amdgcn_sched_barrier(0);                     // reads issued first
        #pragma unroll
        for (int q = 0; q < 4; ++q)
            #pragma unroll
            for (int j = 0; j < 4; ++j)
                acc[q][4 + j] = __builtin_amdgcn_mfma_i32_16x16x64_i8(afc[q], bHi[j], acc[q][4 + j], 0, 0, 0);
        #pragma unroll
        for (int q = 0; q < 4; ++q)
            bHi[q] = *(const i32x4*)&bs[((wn >> 4) + 4 + q) * 1024 + foff];
        asm volatile("s_waitcnt lgkmcnt(0)" ::: "memory");     // frags of i+1 in regs
        __builtin_amdgcn_sched_barrier(0);
        if (((i + 1) & (KT - 1)) == 0) {                       // Horner fold at part edge
            #pragma unroll
            for (int q = 0; q < 4; ++q)
                #pragma unroll
                for (int j = 0; j < 8; ++j)
                    acc[q][j] = acc[q][j] * 256;
        }
        #pragma unroll
        for (int q = 0; q < 4; ++q)
            #pragma unroll
            for (int j = 0; j < 4; ++j)
                acc[q][j] = __builtin_amdgcn_mfma_i32_16x16x64_i8(afn[q], bLo[j], acc[q][j], 0, 0, 0);
        sbuf = (sbuf == 2) ? 0 : sbuf + 1;
        rbuf = (rbuf == 2) ? 0 : rbuf + 1;
    };

    // prologue: stage tiles 0,1; read tile 0; lo-half of tile 0
    stageT(0, 0, 0);
    stageT(0, 1, 1);
    asm volatile("s_waitcnt vmcnt(6)" ::: "memory");
    __builtin_amdgcn_s_barrier();
    {
        const char* as = As;
        const char* bs = Bs;
        #pragma unroll
        for (int q = 0; q < 4; ++q)
            afA[q] = *(const i32x4*)&as[((wm >> 4) + q) * 1024 + foff];
        #pragma unroll
        for (int q = 0; q < 4; ++q) {
            bLo[q] = *(const i32x4*)&bs[((wn >> 4) + q) * 1024 + foff];
            bHi[q] = *(const i32x4*)&bs[((wn >> 4) + 4 + q) * 1024 + foff];
        }
    }
    asm volatile("s_waitcnt lgkmcnt(0)" ::: "memory");
    __builtin_amdgcn_sched_barrier(0);
    #pragma unroll
    for (int q = 0; q < 4; ++q)
        #pragma unroll
        for (int j = 0; j < 4; ++j)
            acc[q][j] = __builtin_amdgcn_mfma_i32_16x16x64_i8(afA[q], bLo[j], acc[q][j], 0, 0, 0);

    for (int i = 0; i < NT - 2; i += 2) {
        body(i, afA, afB);
        body(i + 1, afB, afA);
    }
    body(NT - 2, afA, afB);
    #pragma unroll
    for (int q = 0; q < 4; ++q)
        #pragma unroll
        for (int j = 0; j < 4; ++j)
            acc[q][4 + j] = __builtin_amdgcn_mfma_i32_16x16x64_i8(afB[q], bHi[j], acc[q][4 + j], 0, 0, 0);

    // ---------- fused LIF epilogue: LDS-transpose scan ----------
    const float SCALE = 7.450580596923828e-9f;   // 2^-27
    {
        float bb[8];
        #pragma unroll
        for (int j = 0; j < 8; ++j)
            bb[j] = bias[n0 + wn + j * 16 + rho];
        #pragma unroll
        for (int si = 0; si < 4; ++si)
            #pragma unroll
            for (int j = 0; j < 8; ++j) {
                i32x4 v = acc[si][j];
                f32x4 c;
                #pragma unroll
                for (int r = 0; r < 4; ++r)
                    c[r] = (float)v[r] * SCALE + bb[j];
                acc[si][j] = __builtin_bit_cast(i32x4, c);
            }
    }
    __builtin_amdgcn_s_barrier();                // all waves past their last LDS reads
    {
        char* wb = Smem + wave * 16384;          // per-wave 16KB region
        const int brow = m0 + wm;                // rows b*64 + s
        #pragma unroll
        for (int h = 0; h < 2; ++h) {
            // write 64 cols x 64 s ([col][s] f32, chunk k = s>>2, XOR swizzle)
            #pragma unroll
            for (int si = 0; si < 4; ++si)
                #pragma unroll
                for (int jj = 0; jj < 4; ++jj) {
                    const int c = jj * 16 + rho;
                    const int k = si * 4 + kap;
                    *(f32x4*)(wb + c * 256 + ((k ^ (c & 7)) << 4)) =
                        __builtin_bit_cast(f32x4, acc[si][h * 4 + jj]);
                }
            asm volatile("s_waitcnt lgkmcnt(0)" ::: "memory");
            float col[64];
            #pragma unroll
            for (int k = 0; k < 16; ++k) {
                f32x4 v = *(const f32x4*)(wb + lane * 256 + ((k ^ (lane & 7)) << 4));
                col[k * 4 + 0] = v[0]; col[k * 4 + 1] = v[1];
                col[k * 4 + 2] = v[2]; col[k * 4 + 3] = v[3];
            }
            asm volatile("s_waitcnt lgkmcnt(0)" ::: "memory");
            signed char* So = Sout + (size_t)brow * N + (n0 + wn + h * 64 + lane);
            float m = 0.0f;
            #pragma unroll
            for (int s = 0; s < 64; ++s) {
                float rst = (m > 1.0f) ? 1.0f : 0.0f;
                m = __fsub_rn(__fadd_rn(__fmul_rn(0.9f, m), col[s]), rst);
                So[(size_t)s * N] = (m > 1.0f) ? (signed char)1 : (signed char)0;
            }
        }
    }
}

// ================= i8 GEMM B + fused LIF -> f32 output: block 128x128, wave 64x64 =====
__global__ __launch_bounds__(256, 2)
void snn_gemm_i8_n_lif(const signed char* __restrict__ A,
                       const signed char* __restrict__ Wq,
                       const float* __restrict__ bias,
                       float* __restrict__ Dout,        // [S, Bsz, N] f32 spikes
                       int M, int N, int K, int Bsz) {
    __shared__ __align__(16) char Smem[65536];     // main: As 24KB + Bs 24KB; epi: 4x16KB
    char* As = Smem;
    char* Bs = Smem + 24576;
    const int t    = threadIdx.x;
    const int wave = t >> 6;
    const int lane = t & 63;

    int m_idx, n_idx;
    {
        int gx = gridDim.x, gy = gridDim.y;
        int flat = blockIdx.y * gx + blockIdx.x;
        if ((gy & 7) == 0) {
            int x = flat & 7, local = flat >> 3, h = gy >> 3;
            m_idx = x * h + (local % h);
            n_idx = local / h;
        } else { m_idx = blockIdx.y; n_idx = blockIdx.x; }
    }
    const int m0 = m_idx * 128;
    const int n0 = n_idx * 128;
    const int wm = (wave & 1) * 64;
    const int wn = (wave >> 1) * 64;

    const int srow = lane >> 2;
    const int schk = ((lane & 3) + (lane >> 2) + (lane >> 4)) & 3;
    const int rho  = lane & 15;
    const int kap  = lane >> 4;
    const int foff = ((rho << 2) + ((kap - rho - (rho >> 2)) & 3)) * 16;   // bytes

    const int KT = K >> 6;
    const int NT = 3 * KT;
    const size_t PK = (size_t)N * K;

    size_t aOff[2], bOff[2];
    #pragma unroll
    for (int q = 0; q < 2; ++q) {
        aOff[q] = (size_t)(m0 + (wave * 2 + q) * 16 + srow) * K + schk * 16;
        bOff[q] = (size_t)(n0 + (wave * 2 + q) * 16 + srow) * K + schk * 16;
    }

    i32x4 acc[4][4] = {};
    i32x4 afA[4], afB[4], bLo[2], bHi[2];

    auto stageT = [&](int p, int kt, int bsel) {
        const int kk = kt << 6;
        char* as = As + bsel * 8192;
        char* bs = Bs + bsel * 8192;
        const signed char* Bw = Wq + (size_t)p * PK;
        #pragma unroll
        for (int q = 0; q < 2; ++q) {
            async16(A  + aOff[q] + kk, as + (wave * 2 + q) * 1024 + lane * 16);
            async16(Bw + bOff[q] + kk, bs + (wave * 2 + q) * 1024 + lane * 16);
        }
    };

    int sp = 0, skt = 2;
    int sbuf = 2, rbuf = 1;

    auto body = [&](int i, i32x4* afc, i32x4* afn) {
        if (i + 2 < NT) {
            stageT(sp, skt, sbuf);
            if (++skt == KT) { skt = 0; ++sp; }
            asm volatile("s_waitcnt vmcnt(4)" ::: "memory");
        } else {
            asm volatile("s_waitcnt vmcnt(0)" ::: "memory");
        }
        __builtin_amdgcn_s_barrier();
        const char* as = As + rbuf * 8192;
        const char* bs = Bs + rbuf * 8192;
        #pragma unroll
        for (int q = 0; q < 4; ++q)
            afn[q] = *(const i32x4*)&as[((wm >> 4) + q) * 1024 + foff];
        #pragma unroll
        for (int q = 0; q < 2; ++q)
            bLo[q] = *(const i32x4*)&bs[((wn >> 4) + q) * 1024 + foff];
        __builtin_amdgcn_sched_barrier(0);
        #pragma unroll
        for (int q = 0; q < 4; ++q)
            #pragma unroll
            for (int j = 0; j < 2; ++j)
                acc[q][2 + j] = __builtin_amdgcn_mfma_i32_16x16x64_i8(afc[q], bHi[j], acc[q][2 + j], 0, 0, 0);
        #pragma unroll
        for (int q = 0; q < 2; ++q)
            bHi[q] = *(const i32x4*)&bs[((wn >> 4) + 2 + q) * 1024 + foff];
        asm volatile("s_waitcnt lgkmcnt(0)" ::: "memory");
        __builtin_amdgcn_sched_barrier(0);
        if (((i + 1) & (KT - 1)) == 0) {
            #pragma unroll
            for (int q = 0; q < 4; ++q)
                #pragma unroll
                for (int j = 0; j < 4; ++j)
                    acc[q][j] = acc[q][j] * 256;
        }
        #pragma unroll
        for (int q = 0; q < 4; ++q)
            #pragma unroll
            for (int j = 0; j < 2; ++j)
                acc[q][j] = __builtin_amdgcn_mfma_i32_16x16x64_i8(afn[q], bLo[j], acc[q][j], 0, 0, 0);
        sbuf = (sbuf == 2) ? 0 : sbuf + 1;
        rbuf = (rbuf == 2) ? 0 : rbuf + 1;
    };

    stageT(0, 0, 0);
    stageT(0, 1, 1);
    asm volatile("s_waitcnt vmcnt(4)" ::: "memory");
    __builtin_amdgcn_s_barrier();
    {
        const char* as = As;
        const char* bs = Bs;
        #pragma unroll
        for (int q = 0; q < 4; ++q)
            afA[q] = *(const i32x4*)&as[((wm >> 4) + q) * 1024 + foff];
        #pragma unroll
        for (int q = 0; q < 2; ++q) {
            bLo[q] = *(const i32x4*)&bs[((wn >> 4) + q) * 1024 + foff];
            bHi[q] = *(const i32x4*)&bs[((wn >> 4) + 2 + q) * 1024 + foff];
        }
    }
    asm volatile("s_waitcnt lgkmcnt(0)" ::: "memory");
    __builtin_amdgcn_sched_barrier(0);
    #pragma unroll
    for (int q = 0; q < 4; ++q)
        #pragma unroll
        for (int j = 0; j < 2; ++j)
            acc[q][j] = __builtin_amdgcn_mfma_i32_16x16x64_i8(afA[q], bLo[j], acc[q][j], 0, 0, 0);

    for (int i = 0; i < NT - 2; i += 2) {
        body(i, afA, afB);
        body(i + 1, afB, afA);
    }
    body(NT - 2, afA, afB);
    #pragma unroll
    for (int q = 0; q < 4; ++q)
        #pragma unroll
        for (int j = 0; j < 2; ++j)
            acc[q][2 + j] = __builtin_amdgcn_mfma_i32_16x16x64_i8(afB[q], bHi[j], acc[q][2 + j], 0, 0, 0);

    // ---------- fused LIF epilogue: LDS-transpose scan -> f32 spikes ----------
    const float SCALE = 7.450580596923828e-9f;   // 2^-27
    {
        float bb[4];
        #pragma unroll
        for (int j = 0; j < 4; ++j)
            bb[j] = bias[n0 + wn + j * 16 + rho];
        #pragma unroll
        for (int si = 0; si < 4; ++si)
            #pragma unroll
            for (int j = 0; j < 4; ++j) {
                i32x4 v = acc[si][j];
                f32x4 c;
                #pragma unroll
                for (int r = 0; r < 4; ++r)
                    c[r] = (float)v[r] * SCALE + bb[j];
                acc[si][j] = __builtin_bit_cast(i32x4, c);
            }
    }
    __builtin_amdgcn_s_barrier();
    {
        char* wb = Smem + wave * 16384;
        const int b_idx = (m0 + wm) >> 6;
        // write 64 cols x 64 s
        #pragma unroll
        for (int si = 0; si < 4; ++si)
            #pragma unroll
            for (int j = 0; j < 4; ++j) {
                const int c = j * 16 + rho;
                const int k = si * 4 + kap;
                *(f32x4*)(wb + c * 256 + ((k ^ (c & 7)) << 4)) =
                    __builtin_bit_cast(f32x4, acc[si][j]);
            }
        asm volatile("s_waitcnt lgkmcnt(0)" ::: "memory");
        float col[64];
        #pragma unroll
        for (int k = 0; k < 16; ++k) {
            f32x4 v = *(const f32x4*)(wb + lane * 256 + ((k ^ (lane & 7)) << 4));
            col[k * 4 + 0] = v[0]; col[k * 4 + 1] = v[1];
            col[k * 4 + 2] = v[2]; col[k * 4 + 3] = v[3];
        }
        asm volatile("s_waitcnt lgkmcnt(0)" ::: "memory");
        float* Do = Dout + (size_t)b_idx * N + (n0 + wn + lane);
        float m = 0.0f;
        #pragma unroll
        for (int s = 0; s < 64; ++s) {
            float rst = (m > 1.0f) ? 1.0f : 0.0f;
            m = __fsub_rn(__fadd_rn(__fmul_rn(0.9f, m), col[s]), rst);
            Do[(size_t)s * Bsz * N] = (m > 1.0f) ? 1.0f : 0.0f;
        }
    }
}

// ========== GEMM0 bf16, per-part blocks, pipelined (R10-verified) ==========
__global__ __launch_bounds__(256, 2)
void snn_gemm0_bf16p(const __hip_bfloat16* __restrict__ A,
                     const __hip_bfloat16* __restrict__ Wp,
                     float* __restrict__ Cpart) {
    constexpr int M = 256, N = 1024, K = 512;
    constexpr int KT = K / 32;
    __shared__ __align__(16) char As[3 * 8192];
    __shared__ __align__(16) char Bs[3 * 8192];
    const int t    = threadIdx.x;
    const int wave = t >> 6;
    const int lane = t & 63;

    const int part = blockIdx.z;
    const __hip_bfloat16* Bw = Wp + (size_t)part * N * K;
    float* C = Cpart + (size_t)part * M * N;
    const int m0 = blockIdx.y * 128;
    const int n0 = blockIdx.x * 128;
    const int wm = (wave & 1) * 64;
    const int wn = (wave >> 1) * 64;

    const int srow = lane >> 2;
    const int schk = ((lane & 3) + (lane >> 2) + (lane >> 4)) & 3;
    const int rho  = lane & 15;
    const int kap  = lane >> 4;
    const int foff = ((rho << 2) + ((kap - rho - (rho >> 2)) & 3)) * 16;   // bytes

    size_t aOff[2], bOff[2];
    #pragma unroll
    for (int q = 0; q < 2; ++q) {
        aOff[q] = (size_t)(m0 + (wave * 2 + q) * 16 + srow) * K + schk * 8;
        bOff[q] = (size_t)(n0 + (wave * 2 + q) * 16 + srow) * K + schk * 8;
    }

    f32x4 acc[4][4] = {};
    bf16x8 afA[4], afB[4], bLo[2], bHi[2];

    auto stageT = [&](int kt, int bsel) {
        const int kk = kt << 5;
        char* as = As + bsel * 8192;
        char* bs = Bs + bsel * 8192;
        #pragma unroll
        for (int q = 0; q < 2; ++q) {
            async16(A  + aOff[q] + kk, as + (wave * 2 + q) * 1024 + lane * 16);
            async16(Bw + bOff[q] + kk, bs + (wave * 2 + q) * 1024 + lane * 16);
        }
    };

    int skt = 2;
    int sbuf = 2, rbuf = 1;

    auto body = [&](int i, bf16x8* afc, bf16x8* afn) {
        if (i + 2 < KT) {
            stageT(skt, sbuf);
            ++skt;
            asm volatile("s_waitcnt vmcnt(4)" ::: "memory");
        } else {
            asm volatile("s_waitcnt vmcnt(0)" ::: "memory");
        }
        __builtin_amdgcn_s_barrier();
        const char* as = As + rbuf * 8192;
        const char* bs = Bs + rbuf * 8192;
        #pragma unroll
        for (int q = 0; q < 4; ++q)
            afn[q] = *(const bf16x8*)&as[((wm >> 4) + q) * 1024 + foff];
        #pragma unroll
        for (int q = 0; q < 2; ++q)
            bLo[q] = *(const bf16x8*)&bs[((wn >> 4) + q) * 1024 + foff];
        __builtin_amdgcn_sched_barrier(0);
        #pragma unroll
        for (int q = 0; q < 4; ++q)
            #pragma unroll
            for (int j = 0; j < 2; ++j)
                acc[q][2 + j] = __builtin_amdgcn_mfma_f32_16x16x32_bf16(afc[q], bHi[j], acc[q][2 + j], 0, 0, 0);
        #pragma unroll
        for (int q = 0; q < 2; ++q)
            bHi[q] = *(const bf16x8*)&bs[((wn >> 4) + 2 + q) * 1024 + foff];
        asm volatile("s_waitcnt lgkmcnt(0)" ::: "memory");
        __builtin_amdgcn_sched_barrier(0);
        #pragma unroll
        for (int q = 0; q < 4; ++q)
            #pragma unroll
            for (int j = 0; j < 2; ++j)
                acc[q][j] = __builtin_amdgcn_mfma_f32_16x16x32_bf16(afn[q], bLo[j], acc[q][j], 0, 0, 0);
        sbuf = (sbuf == 2) ? 0 : sbuf + 1;
        rbuf = (rbuf == 2) ? 0 : rbuf + 1;
    };

    stageT(0, 0);
    stageT(1, 1);
    asm volatile("s_waitcnt vmcnt(4)" ::: "memory");
    __builtin_amdgcn_s_barrier();
    {
        const char* as = As;
        const char* bs = Bs;
        #pragma unroll
        for (int q = 0; q < 4; ++q)
            afA[q] = *(const bf16x8*)&as[((wm >> 4) + q) * 1024 + foff];
        #pragma unroll
        for (int q = 0; q < 2; ++q) {
            bLo[q] = *(const bf16x8*)&bs[((wn >> 4) + q) * 1024 + foff];
            bHi[q] = *(const bf16x8*)&bs[((wn >> 4) + 2 + q) * 1024 + foff];
        }
    }
    asm volatile("s_waitcnt lgkmcnt(0)" ::: "memory");
    __builtin_amdgcn_sched_barrier(0);
    #pragma unroll
    for (int q = 0; q < 4; ++q)
        #pragma unroll
        for (int j = 0; j < 2; ++j)
            acc[q][j] = __builtin_amdgcn_mfma_f32_16x16x32_bf16(afA[q], bLo[j], acc[q][j], 0, 0, 0);

    for (int i = 0; i < KT - 2; i += 2) {
        body(i, afA, afB);
        body(i + 1, afB, afA);
    }
    body(KT - 2, afA, afB);
    #pragma unroll
    for (int q = 0; q < 4; ++q)
        #pragma unroll
        for (int j = 0; j < 2; ++j)
            acc[q][2 + j] = __builtin_amdgcn_mfma_f32_16x16x32_bf16(afB[q], bHi[j], acc[q][2 + j], 0, 0, 0);

    #pragma unroll
    for (int i = 0; i < 4; ++i) {
        int mg = m0 + wm + i * 16 + (lane >> 4) * 4;
        #pragma unroll
        for (int j = 0; j < 4; ++j) {
            int ng = n0 + wn + j * 16 + (lane & 15);
            #pragma unroll
            for (int r = 0; r < 4; ++r)
                C[(size_t)(mg + r) * N + ng] = acc[i][j][r];
        }
    }
}

// -------- LIF layer 0: sum 3 part-slabs + bias, scan, b-major i8 spikes --------
__global__ void snn_lif0_sum3(const float4* __restrict__ p, const float4* __restrict__ b4,
                              uchar4* __restrict__ spk) {
    constexpr int MN4 = 256 * 1024 / 4;
    constexpr int H4  = 256;
    int idx = blockIdx.x * blockDim.x + threadIdx.x;
    if (idx >= MN4) return;
    const int b  = idx >> 8;
    const int h4 = idx & 255;
    float4 h = p[idx], mm = p[idx + MN4], l = p[idx + 2 * MN4], bb = b4[h4];
    float4 c;
    c.x = __fadd_rn(__fadd_rn(__fadd_rn(h.x, mm.x), l.x), bb.x);
    c.y = __fadd_rn(__fadd_rn(__fadd_rn(h.y, mm.y), l.y), bb.y);
    c.z = __fadd_rn(__fadd_rn(__fadd_rn(h.z, mm.z), l.z), bb.z);
    c.w = __fadd_rn(__fadd_rn(__fadd_rn(h.w, mm.w), l.w), bb.w);
    uchar4* out = spk + (size_t)b * S_STEPS * H4 + h4;
    float m0 = 0.0f, m1 = 0.0f, m2 = 0.0f, m3 = 0.0f;
    for (int s = 0; s < S_STEPS; ++s) {
        float r0 = (m0 > 1.0f) ? 1.0f : 0.0f;
        float r1 = (m1 > 1.0f) ? 1.0f : 0.0f;
        float r2 = (m2 > 1.0f) ? 1.0f : 0.0f;
        float r3 = (m3 > 1.0f) ? 1.0f : 0.0f;
        m0 = __fsub_rn(__fadd_rn(__fmul_rn(0.9f, m0), c.x), r0);
        m1 = __fsub_rn(__fadd_rn(__fmul_rn(0.9f, m1), c.y), r1);
        m2 = __fsub_rn(__fadd_rn(__fmul_rn(0.9f, m2), c.z), r2);
        m3 = __fsub_rn(__fadd_rn(__fmul_rn(0.9f, m3), c.w), r3);
        uchar4 o;
        o.x = (m0 > 1.0f) ? 1 : 0;
        o.y = (m1 > 1.0f) ? 1 : 0;
        o.z = (m2 > 1.0f) ? 1 : 0;
        o.w = (m3 > 1.0f) ? 1 : 0;
        out[(size_t)s * H4] = o;
    }
}

extern "C" void kernel_launch(void* const* d_in, const int* in_sizes, int n_in,
                              void* d_out, int out_size, void* d_ws, size_t ws_size,
                              hipStream_t stream) {
    const float* x  = (const float*)d_in[0];
    const float* W0 = (const float*)d_in[1];
    const float* b0 = (const float*)d_in[2];
    const float* W1 = (const float*)d_in[3];
    const float* b1 = (const float*)d_in[4];
    const float* W2 = (const float*)d_in[5];
    const float* b2 = (const float*)d_in[6];

    const int B = 256, T = 128, F = 512, H1 = 1024, H2 = 1024, H3 = 512;
    const int SB = S_STEPS * B;            // 16384

    char* w = (char*)d_ws;
    signed char*    spk0 = (signed char*)w;                 w += (size_t)SB * H1;
    signed char*    spk1 = (signed char*)w;                 w += (size_t)SB * H2;
    __hip_bfloat16* r_bf = (__hip_bfloat16*)w;              w += (size_t)B * F * 2;
    float*          cur0p = (float*)w;                      w += (size_t)3 * B * H1 * 4;
    __hip_bfloat16* W0s  = (__hip_bfloat16*)w;              w += (size_t)3 * H1 * F * 2;
    signed char*    W1q  = (signed char*)w;                 w += (size_t)3 * H2 * H1;
    signed char*    W2q  = (signed char*)w;                 w += (size_t)3 * H3 * H2;

    // 1. merged prep
    snn_prep<<<dim3(2560), dim3(256), 0, stream>>>(
        (const float4*)x, (ushort4*)r_bf,
        (const float4*)W0, (ushort4*)W0s,
        (const float4*)W1, (const float4*)W2,
        (char4*)W1q, (char4*)W2q);

    // 2. GEMM0 per part, pipelined
    snn_gemm0_bf16p<<<dim3(H1 / 128, B / 128, 3), dim3(256), 0, stream>>>(
        r_bf, W0s, cur0p);

    // 3. LIF layer 0: sum parts + bias, scan -> spk0 i8 b-major
    snn_lif0_sum3<<<dim3(B * H1 / 4 / 256), dim3(256), 0, stream>>>(
        (const float4*)cur0p, (const float4*)b0, (uchar4*)spk0);

    // 4+5. GEMM1 (R10 triple-buffer) + transpose-scan LIF -> spk1 i8 b-major
    snn_gemm_i8_w_lif<<<dim3(H2 / 256, SB / 128), dim3(256), 0, stream>>>(
        spk0, W1q, b1, spk1, SB, H2, H1);

    // 6+7. GEMM2 + transpose-scan LIF -> d_out f32 [S, B, H3]
    snn_gemm_i8_n_lif<<<dim3(H3 / 128, SB / 128), dim3(256), 0, stream>>>(
        spk1, W2q, b2, (float*)d_out, SB, H3, H2, B);
}